// Round 1
// baseline (118.342 us; speedup 1.0000x reference)
//
#include <hip/hip_runtime.h>

// Problem constants (from the reference).
constexpr int S  = 51;   // seq positions
constexpr int V  = 64;   // vocab
constexpr int E  = 4;    // embedding dim
constexpr int H1 = 5;
constexpr int H2 = 7;
constexpr int D  = 64;   // output dim

// ---------------------------------------------------------------------------
// Kernel 1: build Y[s][v][d] = tanh(W3[s] @ h2(s,v) + b3[s])  (3264 x 64 table)
// The whole MLP depends only on (s, token) -- batch-independent.
// One block per (s,v) pair, one lane per output dim d. The h1/h2 chain is
// recomputed redundantly per lane (it's ~110 FLOP -- irrelevant).
// ---------------------------------------------------------------------------
__global__ void build_table_kernel(const float* __restrict__ emb,
                                   const float* __restrict__ W1,
                                   const float* __restrict__ b1,
                                   const float* __restrict__ W2,
                                   const float* __restrict__ b2,
                                   const float* __restrict__ W3,
                                   const float* __restrict__ b3,
                                   float* __restrict__ Y) {
  const int sv = blockIdx.x;     // 0 .. S*V-1,  sv = s*64 + v
  const int s  = sv >> 6;
  const int d  = threadIdx.x;    // 0..63

  float e[E];
#pragma unroll
  for (int i = 0; i < E; ++i) e[i] = emb[sv * E + i];   // emb[s][v][i]

  float h1[H1];
#pragma unroll
  for (int h = 0; h < H1; ++h) {
    float a = b1[s * H1 + h];
#pragma unroll
    for (int i = 0; i < E; ++i) a = fmaf(W1[(s * H1 + h) * E + i], e[i], a);
    h1[h] = (a >= 0.f) ? a : 0.01f * a;   // leaky_relu, slope 0.01
  }

  float h2[H2];
#pragma unroll
  for (int g = 0; g < H2; ++g) {
    float a = b2[s * H2 + g];
#pragma unroll
    for (int h = 0; h < H1; ++h) a = fmaf(W2[(s * H2 + g) * H1 + h], h1[h], a);
    h2[g] = (a >= 0.f) ? a : 0.01f * a;
  }

  float a = b3[s * D + d];
#pragma unroll
  for (int g = 0; g < H2; ++g) a = fmaf(W3[(s * D + d) * H2 + g], h2[g], a);

  Y[sv * D + d] = tanhf(a);
}

// ---------------------------------------------------------------------------
// Kernel 2: out[b][d] = sum_s Y[s, x[b,s], d]
// Wave = 4 batch rows, lane = d. Tokens for the 4 rows are prefetched once
// (lanes 0..50 hold x[b_i, lane]) and broadcast per-s via __shfl, so the
// inner loop is shfl -> coalesced 256B L2 gather -> fadd. Table (835 KB) is
// L2-resident; HBM traffic is just x reads + out writes (~30 MB).
// ---------------------------------------------------------------------------
__global__ __launch_bounds__(256) void gather_sum_kernel(
    const int* __restrict__ x, const float* __restrict__ Y,
    float* __restrict__ out, int B) {
  const int lane  = threadIdx.x & 63;
  const int wid   = threadIdx.x >> 6;                 // wave id 0..3
  const int bbase = (blockIdx.x * 4 + wid) * 4;       // first of 4 batch rows
  if (bbase >= B) return;

  int tok0 = 0, tok1 = 0, tok2 = 0, tok3 = 0;
  if (lane < S) {
    tok0 = x[(bbase + 0) * S + lane];
    tok1 = x[(bbase + 1) * S + lane];
    tok2 = x[(bbase + 2) * S + lane];
    tok3 = x[(bbase + 3) * S + lane];
  }

  float acc0 = 0.f, acc1 = 0.f, acc2 = 0.f, acc3 = 0.f;
#pragma unroll 4
  for (int s = 0; s < S; ++s) {
    const float* Ys = Y + (s << 12);                  // s*V*D = s*4096
    const int t0 = __shfl(tok0, s);
    const int t1 = __shfl(tok1, s);
    const int t2 = __shfl(tok2, s);
    const int t3 = __shfl(tok3, s);
    acc0 += Ys[(t0 << 6) + lane];
    acc1 += Ys[(t1 << 6) + lane];
    acc2 += Ys[(t2 << 6) + lane];
    acc3 += Ys[(t3 << 6) + lane];
  }

  out[(bbase + 0) * D + lane] = acc0;
  out[(bbase + 1) * D + lane] = acc1;
  out[(bbase + 2) * D + lane] = acc2;
  out[(bbase + 3) * D + lane] = acc3;
}

// ---------------------------------------------------------------------------
extern "C" void kernel_launch(void* const* d_in, const int* in_sizes, int n_in,
                              void* d_out, int out_size, void* d_ws, size_t ws_size,
                              hipStream_t stream) {
  const int*   x   = (const int*)d_in[0];
  const float* emb = (const float*)d_in[1];
  const float* W1  = (const float*)d_in[2];
  const float* b1  = (const float*)d_in[3];
  const float* W2  = (const float*)d_in[4];
  const float* b2  = (const float*)d_in[5];
  const float* W3  = (const float*)d_in[6];
  const float* b3  = (const float*)d_in[7];

  const int B = in_sizes[0] / S;          // 65536
  float* Y = (float*)d_ws;                // S*V*D floats = 835,584 bytes

  // Table rebuild every launch (d_ws is re-poisoned before each timed call).
  build_table_kernel<<<S * V, D, 0, stream>>>(emb, W1, b1, W2, b2, W3, b3, Y);

  // 16 batch rows per 256-thread block.
  const int blocks = (B + 15) / 16;
  gather_sum_kernel<<<blocks, 256, 0, stream>>>(x, Y, (float*)d_out, B);
}

// Round 2
// 97.260 us; speedup vs baseline: 1.2168x; 1.2168x over previous
//
#include <hip/hip_runtime.h>
#include <hip/hip_fp16.h>

// Problem constants (from the reference).
constexpr int S  = 51;   // seq positions
constexpr int V  = 64;   // vocab
constexpr int E  = 4;    // embedding dim
constexpr int H1 = 5;
constexpr int H2 = 7;
constexpr int D  = 64;   // output dim

// ---------------------------------------------------------------------------
// Kernel 1: build fp16 table Y[s][v][d] = tanh(W3[s] @ h2(s,v) + b3[s]).
// Whole MLP depends only on (s, token): 3264 x 64 entries, 417 KB fp16.
// ---------------------------------------------------------------------------
__global__ void build_table_kernel(const float* __restrict__ emb,
                                   const float* __restrict__ W1,
                                   const float* __restrict__ b1,
                                   const float* __restrict__ W2,
                                   const float* __restrict__ b2,
                                   const float* __restrict__ W3,
                                   const float* __restrict__ b3,
                                   __half* __restrict__ Y) {
  const int sv = blockIdx.x;     // sv = s*64 + v
  const int s  = sv >> 6;
  const int d  = threadIdx.x;    // 0..63

  float e[E];
#pragma unroll
  for (int i = 0; i < E; ++i) e[i] = emb[sv * E + i];

  float h1[H1];
#pragma unroll
  for (int h = 0; h < H1; ++h) {
    float a = b1[s * H1 + h];
#pragma unroll
    for (int i = 0; i < E; ++i) a = fmaf(W1[(s * H1 + h) * E + i], e[i], a);
    h1[h] = (a >= 0.f) ? a : 0.01f * a;   // leaky_relu
  }

  float h2[H2];
#pragma unroll
  for (int g = 0; g < H2; ++g) {
    float a = b2[s * H2 + g];
#pragma unroll
    for (int h = 0; h < H1; ++h) a = fmaf(W2[(s * H2 + g) * H1 + h], h1[h], a);
    h2[g] = (a >= 0.f) ? a : 0.01f * a;
  }

  float a = b3[s * D + d];
#pragma unroll
  for (int g = 0; g < H2; ++g) a = fmaf(W3[(s * D + d) * H2 + g], h2[g], a);

  Y[sv * D + d] = __float2half(tanhf(a));
}

// ---------------------------------------------------------------------------
// Kernel 2: out[b][d] = sum_s Y[s, x[b,s], d]
// Wave = 8 batch rows. Lane l: row group rg = l>>3, li = l&7 covers
// d = li*8 .. li*8+7 (8 halves = one 16B dwordx4 per lane -> 1 KB per wave
// per s in a single load instruction). Tokens pre-gathered into 7 regs per
// lane (slot j holds s = j*8+li for this lane's row); broadcast per-s via one
// ds_bpermute shuffle. Accumulate fp32.
// ---------------------------------------------------------------------------
__global__ __launch_bounds__(256) void gather_sum_kernel(
    const int* __restrict__ x, const __half* __restrict__ Y,
    float* __restrict__ out, int B) {
  const int lane  = threadIdx.x & 63;
  const int wid   = threadIdx.x >> 6;                 // wave id 0..3
  const int li    = lane & 7;                         // d-octet index
  const int bbase = (blockIdx.x * 4 + wid) * 8;       // first of 8 batch rows
  const int row   = bbase + (lane >> 3);              // this lane's batch row

  // Pre-gather tokens: tok[j] = x[row, j*8 + li]  (covers s = 0..55 >= S)
  int tok[7];
#pragma unroll
  for (int j = 0; j < 7; ++j) {
    const int s = j * 8 + li;
    tok[j] = (s < S) ? x[row * S + s] : 0;
  }

  float acc[8];
#pragma unroll
  for (int k = 0; k < 8; ++k) acc[k] = 0.f;

  const __half* Ybase = Y + (li << 3);                // + d offset (8 halves)
  const int rgsel = lane & 56;                        // rg<<3

#pragma unroll
  for (int s = 0; s < S; ++s) {
    // Token for (this lane's row, s): held by lane rg*8 + (s&7), slot s>>3.
    const int t = __shfl(tok[s >> 3], rgsel | (s & 7), 64);
    const uint4 v = *reinterpret_cast<const uint4*>(Ybase + (s << 12) + (t << 6));
    union { uint4 u; __half2 h[4]; } cv; cv.u = v;
#pragma unroll
    for (int k = 0; k < 4; ++k) {
      const float2 f = __half22float2(cv.h[k]);
      acc[2 * k]     += f.x;
      acc[2 * k + 1] += f.y;
    }
  }

  // Row's 256B output is written by its 8 lanes, 32B each -> wave writes
  // 2 KB contiguous (8 consecutive rows).
  float4* o = reinterpret_cast<float4*>(out + row * D + (li << 3));
  o[0] = make_float4(acc[0], acc[1], acc[2], acc[3]);
  o[1] = make_float4(acc[4], acc[5], acc[6], acc[7]);
}

// ---------------------------------------------------------------------------
extern "C" void kernel_launch(void* const* d_in, const int* in_sizes, int n_in,
                              void* d_out, int out_size, void* d_ws, size_t ws_size,
                              hipStream_t stream) {
  const int*   x   = (const int*)d_in[0];
  const float* emb = (const float*)d_in[1];
  const float* W1  = (const float*)d_in[2];
  const float* b1  = (const float*)d_in[3];
  const float* W2  = (const float*)d_in[4];
  const float* b2  = (const float*)d_in[5];
  const float* W3  = (const float*)d_in[6];
  const float* b3  = (const float*)d_in[7];

  const int B = in_sizes[0] / S;          // 65536
  __half* Y = (__half*)d_ws;              // S*V*D halves = 417,792 bytes

  build_table_kernel<<<S * V, D, 0, stream>>>(emb, W1, b1, W2, b2, W3, b3, Y);

  // 32 batch rows per 256-thread block (8 per wave).
  const int blocks = B / 32;              // 2048
  gather_sum_kernel<<<blocks, 256, 0, stream>>>(x, Y, (float*)d_out, B);
}